// Round 6
// baseline (137.770 us; speedup 1.0000x reference)
//
#include <hip/hip_runtime.h>
#include <hip/hip_bf16.h>

typedef _Float16 half2v __attribute__((ext_vector_type(2)));
typedef _Float16 half8 __attribute__((ext_vector_type(8)));
typedef __attribute__((ext_vector_type(4))) float floatx4;
typedef __attribute__((ext_vector_type(4))) unsigned int uintx4;

#define GLOBAL_AS __attribute__((address_space(1)))
#define LDS_AS __attribute__((address_space(3)))

// async 16B/lane global->LDS DMA. LDS dest = WAVE-uniform base + lane*16.
__device__ __forceinline__ void async_ld16(const void* g, void* l) {
  __builtin_amdgcn_global_load_lds((const GLOBAL_AS unsigned int*)g,
                                   (LDS_AS unsigned int*)l, 16, 0, 0);
}

__device__ __forceinline__ half2v h2(float v) {
  return (half2v){(_Float16)v, (_Float16)v};
}

// tanh(x0),tanh(x1) -> packed-f16 Legendre P1..P8 for BOTH elements.
// fa0 = low halves (elem0), fa1 = high halves (elem1). ~42 VALU total.
__device__ __forceinline__ void legendre2_f16(float xv0, float xv1,
                                              half8* fa0, half8* fa1) {
  float e0 = __builtin_amdgcn_exp2f(xv0 * 2.885390081777927f); // 2*log2(e)
  float t0 = 1.0f - 2.0f * __builtin_amdgcn_rcpf(e0 + 1.0f);
  float e1 = __builtin_amdgcn_exp2f(xv1 * 2.885390081777927f);
  float t1 = 1.0f - 2.0f * __builtin_amdgcn_rcpf(e1 + 1.0f);
  half2v t;
  { auto tt = __builtin_amdgcn_cvt_pkrtz(t0, t1); __builtin_memcpy(&t, &tt, 4); }
  // P_k = u + c_k*(u - P_{k-2}), u = t*P_{k-1}, c_k=(k-1)/k   (packed, 3 ops/deg)
  half2v p1 = t;
  half2v u2 = t * p1, w2 = u2 - h2(1.0f);  half2v p2 = h2(0.5f)      * w2 + u2;
  half2v u3 = t * p2, w3 = u3 - p1;        half2v p3 = h2(2.0f/3.0f) * w3 + u3;
  half2v u4 = t * p3, w4 = u4 - p2;        half2v p4 = h2(0.75f)     * w4 + u4;
  half2v u5 = t * p4, w5 = u5 - p3;        half2v p5 = h2(0.8f)      * w5 + u5;
  half2v u6 = t * p5, w6 = u6 - p4;        half2v p6 = h2(5.0f/6.0f) * w6 + u6;
  half2v u7 = t * p6, w7 = u7 - p5;        half2v p7 = h2(6.0f/7.0f) * w7 + u7;
  half2v u8 = t * p7, w8 = u8 - p6;        half2v p8 = h2(7.0f/8.0f) * w8 + u8;
  unsigned P[8];
  __builtin_memcpy(&P[0], &p1, 4); __builtin_memcpy(&P[1], &p2, 4);
  __builtin_memcpy(&P[2], &p3, 4); __builtin_memcpy(&P[3], &p4, 4);
  __builtin_memcpy(&P[4], &p5, 4); __builtin_memcpy(&P[5], &p6, 4);
  __builtin_memcpy(&P[6], &p7, 4); __builtin_memcpy(&P[7], &p8, 4);
  union { unsigned u[4]; half8 h; } a0, a1;
#pragma unroll
  for (int j = 0; j < 4; ++j) {
    a0.u[j] = __builtin_amdgcn_perm(P[2*j+1], P[2*j], 0x05040100u); // low halves
    a1.u[j] = __builtin_amdgcn_perm(P[2*j+1], P[2*j], 0x07060302u); // high halves
  }
  *fa0 = a0.h;
  *fa1 = a1.h;
}

// ---- kernel 1: c_basis fp32 -> f16, transposed to ws[i][o][d] (256 KB) ----
__global__ void conv_kernel(const float* __restrict__ cb, _Float16* __restrict__ ws) {
  int t = blockIdx.x * 128 + threadIdx.x;   // 0..16383 = (o,i)
  int o = t >> 8;
  int i = t & 255;
  const floatx4* s = (const floatx4*)(cb + ((size_t)o * 256 + i) * 8);
  floatx4 v0 = s[0], v1 = s[1];
  union { _Float16 h[8]; uintx4 u; } w;
  w.h[0] = (_Float16)v0.x; w.h[1] = (_Float16)v0.y;
  w.h[2] = (_Float16)v0.z; w.h[3] = (_Float16)v0.w;
  w.h[4] = (_Float16)v1.x; w.h[5] = (_Float16)v1.y;
  w.h[6] = (_Float16)v1.z; w.h[7] = (_Float16)v1.w;
  *(uintx4*)(ws + (size_t)i * 512 + o * 8) = w.u;
}

// ---- kernel 2: barrier-free main loop, wave-private LDS staging ----
// 256 thr = 4 waves (kh = wid>>1 K-half, rh = wid&1 row-half), 64 rows/block,
// grid 1024, LDS 32 KB. NO inter-wave sharing in the main loop -> zero
// s_barrier; each wave self-paces on R3-verified sched_barrier-pinned
// vmcnt gates (N = 4 + 2*DOX; depth-1 B pipeline).
// i-map (R3-verified): i = kh*128 + q*32 + s, s = step 0..31 (q = lane>>4).
// B: per step, wave DMAs its 4 i-rows (i = kh*128 + {0,32,64,96} + s; 1 KB
// each) into a PRIVATE 4 KB double-buffer bt[wid][s&1].
// x: per lane float4 per 4-step group (cols kh*128 + q*32 + 4g..+3), rolling
// 3-deep register window, normal cached loads (x is L3-resident).
// Epilogue (R5-verified): kh-partial reduction through LDS + bias + store.
__global__ __launch_bounds__(256, 4) void kan_kernel(
    const float* __restrict__ x, const _Float16* __restrict__ ws,
    const float* __restrict__ bias, float* __restrict__ y) {
  // [wave][buf][j*512 + o*8 + d] halves; 4*2*2048*2B = 32 KB
  __shared__ __align__(16) _Float16 bt[4][2][2048];

  const int tid  = threadIdx.x;
  const int wid  = tid >> 6;     // 0..3
  const int kh   = wid >> 1;     // K-half
  const int rh   = wid & 1;      // row-half
  const int lane = tid & 63;
  const int m    = lane & 15;
  const int q    = lane >> 4;
  const int rb   = blockIdx.x * 64;

  floatx4 acc[2][4];
#pragma unroll
  for (int a = 0; a < 2; ++a)
#pragma unroll
    for (int nt = 0; nt < 4; ++nt) acc[a][nt] = (floatx4){0.f, 0.f, 0.f, 0.f};

  // B staging src: DMA j loads i-row i = kh*128 + j*32 + s (1 KB each)
  const _Float16* bs0 = ws + (size_t)(kh * 128 +  0) * 512 + lane * 8;
  const _Float16* bs1 = ws + (size_t)(kh * 128 + 32) * 512 + lane * 8;
  const _Float16* bs2 = ws + (size_t)(kh * 128 + 64) * 512 + lane * 8;
  const _Float16* bs3 = ws + (size_t)(kh * 128 + 96) * 512 + lane * 8;

  // x: rows rb+rh*32+m (stream 0) and +16 (stream 1); cols kh*128+q*32+...
  const float* xp0 = x + (size_t)(rb + rh * 32 + m) * 256 + kh * 128 + q * 32;
  const float* xp1 = xp0 + 16 * 256;

  // rolling 3-deep x window: slot g%3 holds group g (4 cols = steps 4g..4g+3)
  floatx4 xs0[3], xs1[3];
  xs0[0] = *(const floatx4*)(xp0);     xs1[0] = *(const floatx4*)(xp1);
  xs0[1] = *(const floatx4*)(xp0 + 4); xs1[1] = *(const floatx4*)(xp1 + 4);
  __builtin_amdgcn_sched_barrier(0);

  // prologue: stage step 0 into buf 0
  {
    _Float16* ld = &bt[wid][0][0];
    async_ld16(bs0, ld);        async_ld16(bs1, ld + 512);
    async_ld16(bs2, ld + 1024); async_ld16(bs3, ld + 1536);
    bs0 += 512; bs1 += 512; bs2 += 512; bs3 += 512;
  }
  __builtin_amdgcn_sched_barrier(0);

#define CHUNK(ch, N, DOX)                                                      \
  {                                                                            \
    if constexpr (DOX) {                                                       \
      constexpr int gp = (ch) / 4 + 2;                                         \
      xs0[gp % 3] = *(const floatx4*)(xp0 + gp * 4);                           \
      xs1[gp % 3] = *(const floatx4*)(xp1 + gp * 4);                           \
    }                                                                          \
    __builtin_amdgcn_sched_barrier(0);                                         \
    if constexpr ((ch) < 31) {                                                 \
      _Float16* ld = &bt[wid][((ch) + 1) & 1][0];                              \
      async_ld16(bs0, ld);        async_ld16(bs1, ld + 512);                   \
      async_ld16(bs2, ld + 1024); async_ld16(bs3, ld + 1536);                  \
      bs0 += 512; bs1 += 512; bs2 += 512; bs3 += 512;                          \
    }                                                                          \
    __builtin_amdgcn_sched_barrier(0);                                         \
    half8 f0, f1;                                                              \
    legendre2_f16(xs0[((ch) / 4) % 3][(ch) % 4],                               \
                  xs1[((ch) / 4) % 3][(ch) % 4], &f0, &f1);                    \
    asm volatile("s_waitcnt vmcnt(" #N ")" ::: "memory");                      \
    const _Float16* bp = &bt[wid][(ch) & 1][q * 512 + m * 8];                  \
    half8 fb0 = *(const half8*)(bp + 0);                                       \
    half8 fb1 = *(const half8*)(bp + 128);                                     \
    half8 fb2 = *(const half8*)(bp + 256);                                     \
    half8 fb3 = *(const half8*)(bp + 384);                                     \
    __builtin_amdgcn_s_setprio(1);                                             \
    acc[0][0] = __builtin_amdgcn_mfma_f32_16x16x32_f16(f0, fb0, acc[0][0], 0, 0, 0); \
    acc[1][0] = __builtin_amdgcn_mfma_f32_16x16x32_f16(f1, fb0, acc[1][0], 0, 0, 0); \
    acc[0][1] = __builtin_amdgcn_mfma_f32_16x16x32_f16(f0, fb1, acc[0][1], 0, 0, 0); \
    acc[1][1] = __builtin_amdgcn_mfma_f32_16x16x32_f16(f1, fb1, acc[1][1], 0, 0, 0); \
    acc[0][2] = __builtin_amdgcn_mfma_f32_16x16x32_f16(f0, fb2, acc[0][2], 0, 0, 0); \
    acc[1][2] = __builtin_amdgcn_mfma_f32_16x16x32_f16(f1, fb2, acc[1][2], 0, 0, 0); \
    acc[0][3] = __builtin_amdgcn_mfma_f32_16x16x32_f16(f0, fb3, acc[0][3], 0, 0, 0); \
    acc[1][3] = __builtin_amdgcn_mfma_f32_16x16x32_f16(f1, fb3, acc[1][3], 0, 0, 0); \
    __builtin_amdgcn_s_setprio(0);                                             \
  }

  CHUNK(0, 6, 1)  CHUNK(1, 4, 0)  CHUNK(2, 4, 0)  CHUNK(3, 4, 0)
  CHUNK(4, 6, 1)  CHUNK(5, 4, 0)  CHUNK(6, 4, 0)  CHUNK(7, 4, 0)
  CHUNK(8, 6, 1)  CHUNK(9, 4, 0)  CHUNK(10, 4, 0) CHUNK(11, 4, 0)
  CHUNK(12, 6, 1) CHUNK(13, 4, 0) CHUNK(14, 4, 0) CHUNK(15, 4, 0)
  CHUNK(16, 6, 1) CHUNK(17, 4, 0) CHUNK(18, 4, 0) CHUNK(19, 4, 0)
  CHUNK(20, 6, 1) CHUNK(21, 4, 0) CHUNK(22, 4, 0) CHUNK(23, 4, 0)
  CHUNK(24, 4, 0) CHUNK(25, 4, 0) CHUNK(26, 4, 0) CHUNK(27, 4, 0)
  CHUNK(28, 4, 0) CHUNK(29, 4, 0) CHUNK(30, 4, 0) CHUNK(31, 0, 0)
#undef CHUNK

  // ---- epilogue: reduce the two K-partials through LDS, add bias, store ----
  float* red = (float*)&bt[0][0][0];   // 16 KB scratch, reuse staging LDS
  __syncthreads();                     // all waves past vmcnt(0) + compute
  if (kh) {
#pragma unroll
    for (int a = 0; a < 2; ++a)
#pragma unroll
      for (int nt = 0; nt < 4; ++nt)
        *(floatx4*)(red + ((rh * 8 + a * 4 + nt) * 64 + lane) * 4) = acc[a][nt];
  }
  __syncthreads();
  if (!kh) {
    float bv[4];
#pragma unroll
    for (int nt = 0; nt < 4; ++nt) bv[nt] = bias[nt * 16 + m];
#pragma unroll
    for (int a = 0; a < 2; ++a) {
      int gr0 = rb + rh * 32 + a * 16 + q * 4;
#pragma unroll
      for (int nt = 0; nt < 4; ++nt) {
        floatx4 p = *(const floatx4*)(red + ((rh * 8 + a * 4 + nt) * 64 + lane) * 4);
#pragma unroll
        for (int r = 0; r < 4; ++r) {
          y[(size_t)(gr0 + r) * 64 + nt * 16 + m] = acc[a][nt][r] + p[r] + bv[nt];
        }
      }
    }
  }
}

extern "C" void kernel_launch(void* const* d_in, const int* in_sizes, int n_in,
                              void* d_out, int out_size, void* d_ws, size_t ws_size,
                              hipStream_t stream) {
  const float* x    = (const float*)d_in[0];
  const float* cb   = (const float*)d_in[1];
  const float* bias = (const float*)d_in[2];
  float* y = (float*)d_out;
  _Float16* ws = (_Float16*)d_ws;
  int batch = in_sizes[0] / 256;  // 65536
  hipLaunchKernelGGL(conv_kernel, dim3(128), dim3(128), 0, stream, cb, ws);
  hipLaunchKernelGGL(kan_kernel, dim3(batch / 64), dim3(256), 0, stream, x, ws, bias, y);
}

// Round 7
// 119.648 us; speedup vs baseline: 1.1515x; 1.1515x over previous
//
#include <hip/hip_runtime.h>
#include <hip/hip_bf16.h>

typedef _Float16 half2v __attribute__((ext_vector_type(2)));
typedef _Float16 half8 __attribute__((ext_vector_type(8)));
typedef __attribute__((ext_vector_type(4))) float floatx4;
typedef __attribute__((ext_vector_type(4))) unsigned int uintx4;

#define GLOBAL_AS __attribute__((address_space(1)))
#define LDS_AS __attribute__((address_space(3)))

// async 16B/lane global->LDS DMA. LDS dest = WAVE-uniform base + lane*16.
__device__ __forceinline__ void async_ld16(const void* g, void* l) {
  __builtin_amdgcn_global_load_lds((const GLOBAL_AS unsigned int*)g,
                                   (LDS_AS unsigned int*)l, 16, 0, 0);
}

__device__ __forceinline__ half2v h2(float v) {
  return (half2v){(_Float16)v, (_Float16)v};
}

// tanh(x0),tanh(x1) -> packed-f16 Legendre P1..P8 for BOTH elements.
// fa0 = low halves (elem0), fa1 = high halves (elem1). ~42 VALU total.
__device__ __forceinline__ void legendre2_f16(float xv0, float xv1,
                                              half8* fa0, half8* fa1) {
  float e0 = __builtin_amdgcn_exp2f(xv0 * 2.885390081777927f); // 2*log2(e)
  float t0 = 1.0f - 2.0f * __builtin_amdgcn_rcpf(e0 + 1.0f);
  float e1 = __builtin_amdgcn_exp2f(xv1 * 2.885390081777927f);
  float t1 = 1.0f - 2.0f * __builtin_amdgcn_rcpf(e1 + 1.0f);
  half2v t;
  { auto tt = __builtin_amdgcn_cvt_pkrtz(t0, t1); __builtin_memcpy(&t, &tt, 4); }
  // P_k = u + c_k*(u - P_{k-2}), u = t*P_{k-1}, c_k=(k-1)/k   (packed, 3 ops/deg)
  half2v p1 = t;
  half2v u2 = t * p1, w2 = u2 - h2(1.0f);  half2v p2 = h2(0.5f)      * w2 + u2;
  half2v u3 = t * p2, w3 = u3 - p1;        half2v p3 = h2(2.0f/3.0f) * w3 + u3;
  half2v u4 = t * p3, w4 = u4 - p2;        half2v p4 = h2(0.75f)     * w4 + u4;
  half2v u5 = t * p4, w5 = u5 - p3;        half2v p5 = h2(0.8f)      * w5 + u5;
  half2v u6 = t * p5, w6 = u6 - p4;        half2v p6 = h2(5.0f/6.0f) * w6 + u6;
  half2v u7 = t * p6, w7 = u7 - p5;        half2v p7 = h2(6.0f/7.0f) * w7 + u7;
  half2v u8 = t * p7, w8 = u8 - p6;        half2v p8 = h2(7.0f/8.0f) * w8 + u8;
  unsigned P[8];
  __builtin_memcpy(&P[0], &p1, 4); __builtin_memcpy(&P[1], &p2, 4);
  __builtin_memcpy(&P[2], &p3, 4); __builtin_memcpy(&P[3], &p4, 4);
  __builtin_memcpy(&P[4], &p5, 4); __builtin_memcpy(&P[5], &p6, 4);
  __builtin_memcpy(&P[6], &p7, 4); __builtin_memcpy(&P[7], &p8, 4);
  union { unsigned u[4]; half8 h; } a0, a1;
#pragma unroll
  for (int j = 0; j < 4; ++j) {
    a0.u[j] = __builtin_amdgcn_perm(P[2*j+1], P[2*j], 0x05040100u); // low halves
    a1.u[j] = __builtin_amdgcn_perm(P[2*j+1], P[2*j], 0x07060302u); // high halves
  }
  *fa0 = a0.h;
  *fa1 = a1.h;
}

// ---- kernel 1: c_basis fp32 -> f16, transposed to ws[i][o][d] (256 KB) ----
__global__ void conv_kernel(const float* __restrict__ cb, _Float16* __restrict__ ws) {
  int t = blockIdx.x * 128 + threadIdx.x;   // 0..16383 = (o,i)
  int o = t >> 8;
  int i = t & 255;
  const floatx4* s = (const floatx4*)(cb + ((size_t)o * 256 + i) * 8);
  floatx4 v0 = s[0], v1 = s[1];
  union { _Float16 h[8]; uintx4 u; } w;
  w.h[0] = (_Float16)v0.x; w.h[1] = (_Float16)v0.y;
  w.h[2] = (_Float16)v0.z; w.h[3] = (_Float16)v0.w;
  w.h[4] = (_Float16)v1.x; w.h[5] = (_Float16)v1.y;
  w.h[6] = (_Float16)v1.z; w.h[7] = (_Float16)v1.w;
  *(uintx4*)(ws + (size_t)i * 512 + o * 8) = w.u;
}

// ---- kernel 2: R5 discipline, MB=128 (amortized barriers/staging) ----
// 512 thr = 8 waves (kh = wid>>2 K-half, rh = wid&3 row-quarter), 128 rows/
// block, grid 512 -> 2 blocks/CU (LDS 48 KB) = 16 waves/CU = 4 waves/SIMD.
// 16 steps; step stages 16 B i-rows (slot t=0..15 -> i = (t>>3)*128 + step*8
// + (t&7); wave stages t = wid*2, wid*2+1) + 8 KB x (128 rows x 16 cols =
// two 8-col panels), consumed next step. R5-verified discipline per step:
// WAR barrier -> stage(step+1) [3 DMA/wave] -> vmcnt(3) [drains own step-ch
// DMAs; RAW barrier then covers all waves] -> compute.
// x LDS: 16B units, unit(row,p) stored at p' = p ^ ((row>>1)&3) (both-sides
// XOR swizzle, R5-verified 0 conflicts). Wave (kh,rh) reads
// x[rh*32+m(+16)][panel kh*2+ks, elem q] and B slot kh*8+ks*4+q (fragment
// q*512+m*8, +nt*128 — R0/R5-verified). Epilogue: kh-reduction via LDS.
#define NSTEP 16

__global__ __launch_bounds__(512, 4) void kan_kernel(
    const float* __restrict__ x, const _Float16* __restrict__ ws,
    const float* __restrict__ bias, float* __restrict__ y) {
  __shared__ __align__(16) _Float16 bt[2][8192]; // 16 slots x 512h, dbuf: 32 KB
  __shared__ __align__(16) float xs[2][2048];    // 128 rows x 16 cols, dbuf: 16 KB

  const int tid  = threadIdx.x;
  const int wid  = tid >> 6;     // 0..7
  const int kh   = wid >> 2;     // K-half
  const int rh   = wid & 3;      // row-quarter
  const int lane = tid & 63;
  const int m    = lane & 15;
  const int q    = lane >> 4;
  const int rb   = blockIdx.x * 128;

  floatx4 acc[2][4];
#pragma unroll
  for (int a = 0; a < 2; ++a)
#pragma unroll
    for (int nt = 0; nt < 4; ++nt) acc[a][nt] = (floatx4){0.f, 0.f, 0.f, 0.f};

  // B DMA src: 2 slots t = wid*2 + j; i-row i = (t>>3)*128 + step*8 + (t&7)
  const _Float16* bsrc0;
  const _Float16* bsrc1;
  {
    int t0 = wid * 2, t1 = wid * 2 + 1;
    bsrc0 = ws + (size_t)((t0 >> 3) * 128 + (t0 & 7)) * 512 + lane * 8;
    bsrc1 = ws + (size_t)((t1 >> 3) * 128 + (t1 & 7)) * 512 + lane * 8;
  }

  // x DMA src: unit u = wid*64 + lane; row = u>>2, stored piece p' = u&3,
  // actual piece p = p' ^ ((row>>1)&3); col = (p>>1)*128 + (p&1)*4 + step*8
  const float* xsrc;
  {
    int u = wid * 64 + lane;
    int row = u >> 2;
    int p = (u & 3) ^ ((row >> 1) & 3);
    xsrc = x + (size_t)(rb + row) * 256 + (p >> 1) * 128 + (p & 1) * 4;
  }

  // 3 DMAs per wave per step: 2 B i-rows (1 KB each) + 1 x slot (1 KB)
  auto stage = [&](int b) {
    async_ld16(bsrc0, &bt[b][(wid * 2 + 0) * 512]);
    async_ld16(bsrc1, &bt[b][(wid * 2 + 1) * 512]);
    bsrc0 += 8 * 512; bsrc1 += 8 * 512;
    async_ld16(xsrc, &xs[b][wid * 256]);
    xsrc += 8;
  };

  stage(0);

  const int row0 = rh * 32 + m;          // row-stream 0 (stream 1 = +16)
  const int sw   = (row0 >> 1) & 3;      // x swizzle key (same for row0+16)

#pragma unroll 2
  for (int ch = 0; ch < NSTEP; ++ch) {
    const int buf = ch & 1;
    // WAR: all 8 waves done computing step ch-1 (which read buf^1)
    asm volatile("s_barrier" ::: "memory");
    if (ch + 1 < NSTEP) {
      stage(buf ^ 1);
      asm volatile("s_waitcnt vmcnt(3)" ::: "memory"); // own step-ch DMAs landed
    } else {
      asm volatile("s_waitcnt vmcnt(0)" ::: "memory");
    }
    // RAW: ALL waves' step-ch slices landed
    asm volatile("s_barrier" ::: "memory");

#pragma unroll
    for (int ks = 0; ks < 2; ++ks) {
      const int xi = row0 * 16 + (((kh * 2 + ks) ^ sw) << 2) + q;
      float xv0 = xs[buf][xi];
      float xv1 = xs[buf][xi + 256];     // row0+16 -> +16*16 floats
      half8 f0, f1;
      legendre2_f16(xv0, xv1, &f0, &f1);
      const _Float16* bp = &bt[buf][(kh * 8 + ks * 4 + q) * 512 + m * 8];
      half8 fb0 = *(const half8*)(bp + 0);
      half8 fb1 = *(const half8*)(bp + 128);
      half8 fb2 = *(const half8*)(bp + 256);
      half8 fb3 = *(const half8*)(bp + 384);
      __builtin_amdgcn_s_setprio(1);
      acc[0][0] = __builtin_amdgcn_mfma_f32_16x16x32_f16(f0, fb0, acc[0][0], 0, 0, 0);
      acc[1][0] = __builtin_amdgcn_mfma_f32_16x16x32_f16(f1, fb0, acc[1][0], 0, 0, 0);
      acc[0][1] = __builtin_amdgcn_mfma_f32_16x16x32_f16(f0, fb1, acc[0][1], 0, 0, 0);
      acc[1][1] = __builtin_amdgcn_mfma_f32_16x16x32_f16(f1, fb1, acc[1][1], 0, 0, 0);
      acc[0][2] = __builtin_amdgcn_mfma_f32_16x16x32_f16(f0, fb2, acc[0][2], 0, 0, 0);
      acc[1][2] = __builtin_amdgcn_mfma_f32_16x16x32_f16(f1, fb2, acc[1][2], 0, 0, 0);
      acc[0][3] = __builtin_amdgcn_mfma_f32_16x16x32_f16(f0, fb3, acc[0][3], 0, 0, 0);
      acc[1][3] = __builtin_amdgcn_mfma_f32_16x16x32_f16(f1, fb3, acc[1][3], 0, 0, 0);
      __builtin_amdgcn_s_setprio(0);
    }
  }

  // ---- epilogue: reduce the two K-partials through LDS, add bias, store ----
  float* red = (float*)&bt[0][0];        // 32 KB scratch, reuse staging LDS
  __syncthreads();                       // all waves past vmcnt(0) + compute
  if (kh) {
#pragma unroll
    for (int a = 0; a < 2; ++a)
#pragma unroll
      for (int nt = 0; nt < 4; ++nt)
        *(floatx4*)(red + ((rh * 8 + a * 4 + nt) * 64 + lane) * 4) = acc[a][nt];
  }
  __syncthreads();
  if (!kh) {
    float bv[4];
#pragma unroll
    for (int nt = 0; nt < 4; ++nt) bv[nt] = bias[nt * 16 + m];
#pragma unroll
    for (int a = 0; a < 2; ++a) {
      int gr0 = rb + rh * 32 + a * 16 + q * 4;
#pragma unroll
      for (int nt = 0; nt < 4; ++nt) {
        floatx4 p = *(const floatx4*)(red + ((rh * 8 + a * 4 + nt) * 64 + lane) * 4);
#pragma unroll
        for (int r = 0; r < 4; ++r) {
          y[(size_t)(gr0 + r) * 64 + nt * 16 + m] = acc[a][nt][r] + p[r] + bv[nt];
        }
      }
    }
  }
}

extern "C" void kernel_launch(void* const* d_in, const int* in_sizes, int n_in,
                              void* d_out, int out_size, void* d_ws, size_t ws_size,
                              hipStream_t stream) {
  const float* x    = (const float*)d_in[0];
  const float* cb   = (const float*)d_in[1];
  const float* bias = (const float*)d_in[2];
  float* y = (float*)d_out;
  _Float16* ws = (_Float16*)d_ws;
  int batch = in_sizes[0] / 256;  // 65536
  hipLaunchKernelGGL(conv_kernel, dim3(128), dim3(128), 0, stream, cb, ws);
  hipLaunchKernelGGL(kan_kernel, dim3(batch / 128), dim3(512), 0, stream, x, ws, bias, y);
}

// Round 8
// 117.561 us; speedup vs baseline: 1.1719x; 1.0178x over previous
//
#include <hip/hip_runtime.h>
#include <hip/hip_bf16.h>

typedef _Float16 half2v __attribute__((ext_vector_type(2)));
typedef _Float16 half8 __attribute__((ext_vector_type(8)));
typedef __attribute__((ext_vector_type(4))) float floatx4;
typedef __attribute__((ext_vector_type(4))) unsigned int uintx4;

#define GLOBAL_AS __attribute__((address_space(1)))
#define LDS_AS __attribute__((address_space(3)))

// async 16B/lane global->LDS DMA. LDS dest = WAVE-uniform base + lane*16.
__device__ __forceinline__ void async_ld16(const void* g, void* l) {
  __builtin_amdgcn_global_load_lds((const GLOBAL_AS unsigned int*)g,
                                   (LDS_AS unsigned int*)l, 16, 0, 0);
}

__device__ __forceinline__ half2v h2(float v) {
  return (half2v){(_Float16)v, (_Float16)v};
}

// tanh(x0),tanh(x1) -> packed-f16 Legendre P1..P8 for BOTH elements.
// fa0 = low halves (elem0), fa1 = high halves (elem1). ~42 VALU total.
__device__ __forceinline__ void legendre2_f16(float xv0, float xv1,
                                              half8* fa0, half8* fa1) {
  float e0 = __builtin_amdgcn_exp2f(xv0 * 2.885390081777927f); // 2*log2(e)
  float t0 = 1.0f - 2.0f * __builtin_amdgcn_rcpf(e0 + 1.0f);
  float e1 = __builtin_amdgcn_exp2f(xv1 * 2.885390081777927f);
  float t1 = 1.0f - 2.0f * __builtin_amdgcn_rcpf(e1 + 1.0f);
  half2v t;
  { auto tt = __builtin_amdgcn_cvt_pkrtz(t0, t1); __builtin_memcpy(&t, &tt, 4); }
  // P_k = u + c_k*(u - P_{k-2}), u = t*P_{k-1}, c_k=(k-1)/k   (packed, 3 ops/deg)
  half2v p1 = t;
  half2v u2 = t * p1, w2 = u2 - h2(1.0f);  half2v p2 = h2(0.5f)      * w2 + u2;
  half2v u3 = t * p2, w3 = u3 - p1;        half2v p3 = h2(2.0f/3.0f) * w3 + u3;
  half2v u4 = t * p3, w4 = u4 - p2;        half2v p4 = h2(0.75f)     * w4 + u4;
  half2v u5 = t * p4, w5 = u5 - p3;        half2v p5 = h2(0.8f)      * w5 + u5;
  half2v u6 = t * p5, w6 = u6 - p4;        half2v p6 = h2(5.0f/6.0f) * w6 + u6;
  half2v u7 = t * p6, w7 = u7 - p5;        half2v p7 = h2(6.0f/7.0f) * w7 + u7;
  half2v u8 = t * p7, w8 = u8 - p6;        half2v p8 = h2(7.0f/8.0f) * w8 + u8;
  unsigned P[8];
  __builtin_memcpy(&P[0], &p1, 4); __builtin_memcpy(&P[1], &p2, 4);
  __builtin_memcpy(&P[2], &p3, 4); __builtin_memcpy(&P[3], &p4, 4);
  __builtin_memcpy(&P[4], &p5, 4); __builtin_memcpy(&P[5], &p6, 4);
  __builtin_memcpy(&P[6], &p7, 4); __builtin_memcpy(&P[7], &p8, 4);
  union { unsigned u[4]; half8 h; } a0, a1;
#pragma unroll
  for (int j = 0; j < 4; ++j) {
    a0.u[j] = __builtin_amdgcn_perm(P[2*j+1], P[2*j], 0x05040100u); // low halves
    a1.u[j] = __builtin_amdgcn_perm(P[2*j+1], P[2*j], 0x07060302u); // high halves
  }
  *fa0 = a0.h;
  *fa1 = a1.h;
}

// ---- kernel 1: c_basis fp32 -> f16, transposed to ws[i][o][d] (256 KB) ----
__global__ void conv_kernel(const float* __restrict__ cb, _Float16* __restrict__ ws) {
  int t = blockIdx.x * 128 + threadIdx.x;   // 0..16383 = (o,i)
  int o = t >> 8;
  int i = t & 255;
  const floatx4* s = (const floatx4*)(cb + ((size_t)o * 256 + i) * 8);
  floatx4 v0 = s[0], v1 = s[1];
  union { _Float16 h[8]; uintx4 u; } w;
  w.h[0] = (_Float16)v0.x; w.h[1] = (_Float16)v0.y;
  w.h[2] = (_Float16)v0.z; w.h[3] = (_Float16)v0.w;
  w.h[4] = (_Float16)v1.x; w.h[5] = (_Float16)v1.y;
  w.h[6] = (_Float16)v1.z; w.h[7] = (_Float16)v1.w;
  *(uintx4*)(ws + (size_t)i * 512 + o * 8) = w.u;
}

// ---- kernel 2: R7 structure + DEPTH-2 staging (triple buffer) ----
// 512 thr = 8 waves (kh = wid>>2 K-half, rh = wid&3 row-quarter), 128 rows/
// block, grid 512 -> 2 blocks/CU (LDS 72 KB) = 16 waves/CU = 4 waves/SIMD.
// Triple-buffered staging: prologue stages steps 0,1; step ch stages ch+2.
// Gate vmcnt(6) (steps 0-13) drains stage(ch) while leaving stage(ch+1) and
// stage(ch+2) (3 DMAs each) in flight -> every DMA gets ~2 compute phases +
// 2 barrier periods of slack before its gate (attacks the depth-1 jitter
// stall). vmcnt(3) at step 14, vmcnt(0) at 15.
// All maps R0/R5/R7-verified: B slot t=0..15 -> i = (t>>3)*128 + step*8 +
// (t&7) (wave stages t = wid*2, wid*2+1); x 16B units, unit(row,p) stored at
// p' = p ^ ((row>>1)&3); wave (kh,rh) reads x[rh*32+m(+16)][panel kh*2+ks,
// elem q], B slot kh*8+ks*4+q at fragment q*512+m*8 (+nt*128).
// Epilogue: kh-partial reduction through LDS + bias + store (R5-verified).
#define NSTEP 16

__global__ __launch_bounds__(512, 4) void kan_kernel(
    const float* __restrict__ x, const _Float16* __restrict__ ws,
    const float* __restrict__ bias, float* __restrict__ y) {
  __shared__ __align__(16) _Float16 bt[3][8192]; // 16 slots x 512h, 3 bufs: 48 KB
  __shared__ __align__(16) float xs[3][2048];    // 128 rows x 16 cols, 3 bufs: 24 KB

  const int tid  = threadIdx.x;
  const int wid  = tid >> 6;     // 0..7
  const int kh   = wid >> 2;     // K-half
  const int rh   = wid & 3;      // row-quarter
  const int lane = tid & 63;
  const int m    = lane & 15;
  const int q    = lane >> 4;
  const int rb   = blockIdx.x * 128;

  floatx4 acc[2][4];
#pragma unroll
  for (int a = 0; a < 2; ++a)
#pragma unroll
    for (int nt = 0; nt < 4; ++nt) acc[a][nt] = (floatx4){0.f, 0.f, 0.f, 0.f};

  // B DMA src: 2 slots t = wid*2 + j; i-row i = (t>>3)*128 + step*8 + (t&7)
  const _Float16* bsrc0;
  const _Float16* bsrc1;
  {
    int t0 = wid * 2, t1 = wid * 2 + 1;
    bsrc0 = ws + (size_t)((t0 >> 3) * 128 + (t0 & 7)) * 512 + lane * 8;
    bsrc1 = ws + (size_t)((t1 >> 3) * 128 + (t1 & 7)) * 512 + lane * 8;
  }

  // x DMA src: unit u = wid*64 + lane; row = u>>2, stored piece p' = u&3,
  // actual piece p = p' ^ ((row>>1)&3); col = (p>>1)*128 + (p&1)*4 + step*8
  const float* xsrc;
  {
    int u = wid * 64 + lane;
    int row = u >> 2;
    int p = (u & 3) ^ ((row >> 1) & 3);
    xsrc = x + (size_t)(rb + row) * 256 + (p >> 1) * 128 + (p & 1) * 4;
  }

  // 3 DMAs per wave per stage call: 2 B i-rows (1 KB each) + 1 x slot (1 KB)
  auto stage = [&](int b) {
    async_ld16(bsrc0, &bt[b][(wid * 2 + 0) * 512]);
    async_ld16(bsrc1, &bt[b][(wid * 2 + 1) * 512]);
    bsrc0 += 8 * 512; bsrc1 += 8 * 512;
    async_ld16(xsrc, &xs[b][wid * 256]);
    xsrc += 8;
  };

  stage(0);          // step 0 -> buf 0
  stage(1);          // step 1 -> buf 1   (6 DMAs in flight)

  const int row0 = rh * 32 + m;          // row-stream 0 (stream 1 = +16)
  const int sw   = (row0 >> 1) & 3;      // x swizzle key (same for row0+16)

  auto compute = [&](int buf) {
#pragma unroll
    for (int ks = 0; ks < 2; ++ks) {
      const int xi = row0 * 16 + (((kh * 2 + ks) ^ sw) << 2) + q;
      float xv0 = xs[buf][xi];
      float xv1 = xs[buf][xi + 256];     // row0+16 -> +16*16 floats
      half8 f0, f1;
      legendre2_f16(xv0, xv1, &f0, &f1);
      const _Float16* bp = &bt[buf][(kh * 8 + ks * 4 + q) * 512 + m * 8];
      half8 fb0 = *(const half8*)(bp + 0);
      half8 fb1 = *(const half8*)(bp + 128);
      half8 fb2 = *(const half8*)(bp + 256);
      half8 fb3 = *(const half8*)(bp + 384);
      __builtin_amdgcn_s_setprio(1);
      acc[0][0] = __builtin_amdgcn_mfma_f32_16x16x32_f16(f0, fb0, acc[0][0], 0, 0, 0);
      acc[1][0] = __builtin_amdgcn_mfma_f32_16x16x32_f16(f1, fb0, acc[1][0], 0, 0, 0);
      acc[0][1] = __builtin_amdgcn_mfma_f32_16x16x32_f16(f0, fb1, acc[0][1], 0, 0, 0);
      acc[1][1] = __builtin_amdgcn_mfma_f32_16x16x32_f16(f1, fb1, acc[1][1], 0, 0, 0);
      acc[0][2] = __builtin_amdgcn_mfma_f32_16x16x32_f16(f0, fb2, acc[0][2], 0, 0, 0);
      acc[1][2] = __builtin_amdgcn_mfma_f32_16x16x32_f16(f1, fb2, acc[1][2], 0, 0, 0);
      acc[0][3] = __builtin_amdgcn_mfma_f32_16x16x32_f16(f0, fb3, acc[0][3], 0, 0, 0);
      acc[1][3] = __builtin_amdgcn_mfma_f32_16x16x32_f16(f1, fb3, acc[1][3], 0, 0, 0);
      __builtin_amdgcn_s_setprio(0);
    }
  };

  // Step ch: WAR barrier (buf (ch+2)%3 == buf (ch-1)%3 free) -> stage(ch+2)
  // -> vmcnt(N) [drains stage(ch)] -> RAW barrier -> compute(buf ch%3).
#define STEP(ch, N)                                                            \
  {                                                                            \
    asm volatile("s_barrier" ::: "memory");                                    \
    if constexpr ((ch) + 2 < NSTEP) stage(((ch) + 2) % 3);                     \
    asm volatile("s_waitcnt vmcnt(" #N ")" ::: "memory");                      \
    asm volatile("s_barrier" ::: "memory");                                    \
    compute((ch) % 3);                                                         \
  }

  STEP(0, 6)  STEP(1, 6)  STEP(2, 6)  STEP(3, 6)
  STEP(4, 6)  STEP(5, 6)  STEP(6, 6)  STEP(7, 6)
  STEP(8, 6)  STEP(9, 6)  STEP(10, 6) STEP(11, 6)
  STEP(12, 6) STEP(13, 6) STEP(14, 3) STEP(15, 0)
#undef STEP

  // ---- epilogue: reduce the two K-partials through LDS, add bias, store ----
  float* red = (float*)&bt[0][0];        // 32 KB scratch, reuse staging LDS
  __syncthreads();                       // all waves past vmcnt(0) + compute
  if (kh) {
#pragma unroll
    for (int a = 0; a < 2; ++a)
#pragma unroll
      for (int nt = 0; nt < 4; ++nt)
        *(floatx4*)(red + ((rh * 8 + a * 4 + nt) * 64 + lane) * 4) = acc[a][nt];
  }
  __syncthreads();
  if (!kh) {
    float bv[4];
#pragma unroll
    for (int nt = 0; nt < 4; ++nt) bv[nt] = bias[nt * 16 + m];
#pragma unroll
    for (int a = 0; a < 2; ++a) {
      int gr0 = rb + rh * 32 + a * 16 + q * 4;
#pragma unroll
      for (int nt = 0; nt < 4; ++nt) {
        floatx4 p = *(const floatx4*)(red + ((rh * 8 + a * 4 + nt) * 64 + lane) * 4);
#pragma unroll
        for (int r = 0; r < 4; ++r) {
          y[(size_t)(gr0 + r) * 64 + nt * 16 + m] = acc[a][nt][r] + p[r] + bv[nt];
        }
      }
    }
  }
}

extern "C" void kernel_launch(void* const* d_in, const int* in_sizes, int n_in,
                              void* d_out, int out_size, void* d_ws, size_t ws_size,
                              hipStream_t stream) {
  const float* x    = (const float*)d_in[0];
  const float* cb   = (const float*)d_in[1];
  const float* bias = (const float*)d_in[2];
  float* y = (float*)d_out;
  _Float16* ws = (_Float16*)d_ws;
  int batch = in_sizes[0] / 256;  // 65536
  hipLaunchKernelGGL(conv_kernel, dim3(128), dim3(128), 0, stream, cb, ws);
  hipLaunchKernelGGL(kan_kernel, dim3(batch / 128), dim3(512), 0, stream, x, ws, bias, y);
}